// Round 2
// baseline (568.402 us; speedup 1.0000x reference)
//
#include <hip/hip_runtime.h>
#include <hip/hip_bf16.h>

typedef unsigned short u16;
typedef unsigned int u32;

using bf16x8 = __bf16 __attribute__((ext_vector_type(8)));
using s16x8  = short  __attribute__((ext_vector_type(8)));
using f32x4  = float  __attribute__((ext_vector_type(4)));

#define DEV static __device__ __forceinline__

constexpr int T_ = 2048, D_ = 1024;
constexpr int C_ = 64, NC_ = 32;   // chunk length / count
constexpr float EPS_ = 1e-5f;

DEV float bf2f(u16 u) { return __uint_as_float(((u32)u) << 16); }
DEV u16 f2bf(float f) {
  u32 u = __float_as_uint(f);
  return (u16)((u + 0x7fffu + ((u >> 16) & 1u)) >> 16);
}
DEV float swishf(float x) { return x / (1.f + __expf(-x)); }
DEV f32x4 zero4() { f32x4 z = {0.f, 0.f, 0.f, 0.f}; return z; }

// fragment loader: operand stored [outdim][contract] row-major, 16B/lane
DEV bf16x8 ld8(const u16* p, int ld, int r0, int k0, int lane) {
  return *(const bf16x8*)(p + (size_t)(r0 + (lane & 15)) * ld +
                          (size_t)(k0 + ((lane >> 4) << 3)));
}
DEV f32x4 MFMA(bf16x8 a, bf16x8 b, f32x4 c) {
  return __builtin_amdgcn_mfma_f32_16x16x32_bf16(a, b, c, 0, 0, 0);
}

// ---------------- K0: fp32 -> bf16 weight conversion ----------------
__global__ __launch_bounds__(256) void k_cvt(const float* __restrict__ s,
                                             u16* __restrict__ d) {
  const int i = blockIdx.x * 256 + threadIdx.x;
  float4 v = ((const float4*)s)[i];
  uint2 o;
  o.x = (u32)f2bf(v.x) | ((u32)f2bf(v.y) << 16);
  o.y = (u32)f2bf(v.z) | ((u32)f2bf(v.w) << 16);
  ((uint2*)d)[i] = o;
}

// ---------------- K1: RMSNorm (fp32 in -> bf16 h) ----------------
__global__ __launch_bounds__(256) void k_rmsnorm(const float* __restrict__ x,
                                                 const float* __restrict__ w,
                                                 u16* __restrict__ h) {
  const int row = blockIdx.x, tid = threadIdx.x;
  float4 v = ((const float4*)(x + (size_t)row * D_))[tid];
  float ss = v.x * v.x + v.y * v.y + v.z * v.z + v.w * v.w;
#pragma unroll
  for (int d = 32; d >= 1; d >>= 1) ss += __shfl_xor(ss, d, 64);
  __shared__ float red[4];
  if ((tid & 63) == 0) red[tid >> 6] = ss;
  __syncthreads();
  float rs = rsqrtf((red[0] + red[1] + red[2] + red[3]) * (1.f / D_) + EPS_);
  float4 wv = ((const float4*)w)[tid];
  uint2 o;
  o.x = (u32)f2bf(v.x * rs * wv.x) | ((u32)f2bf(v.y * rs * wv.y) << 16);
  o.y = (u32)f2bf(v.z * rs * wv.z) | ((u32)f2bf(v.w * rs * wv.w) << 16);
  *(uint2*)(h + (size_t)row * D_ + tid * 4) = o;
}

// ---------------- K6: swish + RMSNorm (bf16 in -> bf16) ----------------
__global__ __launch_bounds__(256) void k_swishnorm(const u16* __restrict__ x,
                                                   const float* __restrict__ w,
                                                   u16* __restrict__ o) {
  const int row = blockIdx.x, tid = threadIdx.x;
  uint2 pk = *(const uint2*)(x + (size_t)row * D_ + tid * 4);
  float v0 = swishf(bf2f((u16)(pk.x & 0xffff))), v1 = swishf(bf2f((u16)(pk.x >> 16)));
  float v2 = swishf(bf2f((u16)(pk.y & 0xffff))), v3 = swishf(bf2f((u16)(pk.y >> 16)));
  float ss = v0 * v0 + v1 * v1 + v2 * v2 + v3 * v3;
#pragma unroll
  for (int d = 32; d >= 1; d >>= 1) ss += __shfl_xor(ss, d, 64);
  __shared__ float red[4];
  if ((tid & 63) == 0) red[tid >> 6] = ss;
  __syncthreads();
  float rs = rsqrtf((red[0] + red[1] + red[2] + red[3]) * (1.f / D_) + EPS_);
  float4 wv = ((const float4*)w)[tid];
  uint2 ov;
  ov.x = (u32)f2bf(v0 * rs * wv.x) | ((u32)f2bf(v1 * rs * wv.y) << 16);
  ov.y = (u32)f2bf(v2 * rs * wv.z) | ((u32)f2bf(v3 * rs * wv.w) << 16);
  *(uint2*)(o + (size_t)row * D_ + tid * 4) = ov;
}

// ---------------- K2/K7: NT GEMM  out[8192,1024] = A @ W^T ----------------
// MODE 0: z selects weight; z<3 -> swish->bf16 (q/k/v); z==3 -> logsigmoid/16 -> f32 (g)
// MODE 1: identity -> fp32 (final projection)
template <int MODE>
__global__ __launch_bounds__(256) void k_gemm(
    const u16* __restrict__ A, const u16* __restrict__ w0,
    const u16* __restrict__ w1, const u16* __restrict__ w2,
    const u16* __restrict__ w3, u16* __restrict__ oq, u16* __restrict__ okk,
    u16* __restrict__ ov, float* __restrict__ og, float* __restrict__ ofin) {
  __shared__ __align__(16) u16 As[128 * 40];
  __shared__ __align__(16) u16 Bs[128 * 40];
  const int z = blockIdx.z;
  const u16* W = (z == 0) ? w0 : (z == 1) ? w1 : (z == 2) ? w2 : w3;
  const int m0 = blockIdx.x * 128, n0 = blockIdx.y * 128;
  const int tid = threadIdx.x, lane = tid & 63, wvi = tid >> 6;
  const int wr = wvi >> 1, wc = wvi & 1;
  f32x4 acc[4][4];
#pragma unroll
  for (int i = 0; i < 4; i++)
#pragma unroll
    for (int j = 0; j < 4; j++) acc[i][j] = zero4();
  const int srow = tid >> 2, scb = (tid & 3) * 8;
  for (int kk = 0; kk < 1024; kk += 32) {
#pragma unroll
    for (int i = 0; i < 2; i++) {
      int row = srow + 64 * i;
      *(s16x8*)(As + row * 40 + scb) =
          *(const s16x8*)(A + (size_t)(m0 + row) * 1024 + kk + scb);
      *(s16x8*)(Bs + row * 40 + scb) =
          *(const s16x8*)(W + (size_t)(n0 + row) * 1024 + kk + scb);
    }
    __syncthreads();
    bf16x8 af[4], bfr[4];
#pragma unroll
    for (int i = 0; i < 4; i++) af[i] = ld8(As, 40, wr * 64 + 16 * i, 0, lane);
#pragma unroll
    for (int j = 0; j < 4; j++) bfr[j] = ld8(Bs, 40, wc * 64 + 16 * j, 0, lane);
#pragma unroll
    for (int i = 0; i < 4; i++)
#pragma unroll
      for (int j = 0; j < 4; j++) acc[i][j] = MFMA(af[i], bfr[j], acc[i][j]);
    __syncthreads();
  }
  const int q4 = lane >> 4, c15 = lane & 15;
#pragma unroll
  for (int i = 0; i < 4; i++)
#pragma unroll
    for (int j = 0; j < 4; j++)
#pragma unroll
      for (int r = 0; r < 4; r++) {
        int grow = m0 + wr * 64 + 16 * i + 4 * q4 + r;
        int gcol = n0 + wc * 64 + 16 * j + c15;
        size_t idx = (size_t)grow * 1024 + gcol;
        float val = acc[i][j][r];
        if (MODE == 1) {
          ofin[idx] = val;
        } else if (z < 3) {
          u16* o = (z == 0) ? oq : (z == 1) ? okk : ov;
          o[idx] = f2bf(swishf(val));
        } else {
          float g = (val >= 0.f) ? -log1pf(__expf(-val))
                                 : (val - log1pf(__expf(val)));
          og[idx] = g * (1.0f / 16.0f);
        }
      }
}

// ---------------- K3: per-chunk intra states ----------------
// Sk[(p,c)][m][d] = Lam[m] * sum_tau U[tau,m]*k_tau[d],  U = s*exp(-Gc)
// Sv[(p,c)][v][m] = Lam[m] * sum_tau U[tau,m]*v_tau[v]
__global__ __launch_bounds__(256) void k_intra(
    const u16* __restrict__ kg, const u16* __restrict__ vg,
    const float* __restrict__ gg, u16* __restrict__ Sk, u16* __restrict__ Sv,
    float* __restrict__ Lam) {
  __shared__ __align__(16) u16 KV[256 * 72];   // K^T then V^T  [d/v][tau]
  __shared__ __align__(16) u16 Uh[128 * 72];   // U^T half      [m_loc][tau]
  __shared__ float LamH[128];
  const int c = blockIdx.x, p = blockIdx.y;
  const int b = p >> 2, hh = p & 3;
  const int R0 = b * T_ + c * C_, hb = hh * 256;
  const int tid = threadIdx.x, lane = tid & 63, wvi = tid >> 6;
  const int q4 = lane >> 4, c15 = lane & 15;
  const size_t scBase = ((size_t)p * NC_ + c) * (256 * 256);

  // stage K^T
  for (int t = 0; t < C_; t++)
    KV[tid * 72 + t] = kg[(size_t)(R0 + t) * D_ + hb + tid];
  __syncthreads();

  for (int mh = 0; mh < 2; mh++) {
    if (tid < 128) {
      int m = mh * 128 + tid;
      float ga = 0.f;
      for (int t = 0; t < C_; t++) {
        float gv = gg[(size_t)(R0 + t) * D_ + hb + m];
        ga += gv;
        Uh[tid * 72 + t] = f2bf((1.f - __expf(gv)) * __expf(-ga));
      }
      float lam = __expf(ga);
      LamH[tid] = lam;
      Lam[((size_t)p * NC_ + c) * 256 + m] = lam;
    }
    __syncthreads();
    // Hk^T half: [128 m][256 d]; wave rows [32*wvi, +32)
    for (int cb = 0; cb < 4; cb++) {
      f32x4 acc[2][4];
#pragma unroll
      for (int i = 0; i < 2; i++)
#pragma unroll
        for (int j = 0; j < 4; j++) acc[i][j] = zero4();
#pragma unroll
      for (int ks = 0; ks < 2; ks++) {
        bf16x8 af[2], bfr[4];
#pragma unroll
        for (int i = 0; i < 2; i++) af[i] = ld8(Uh, 72, 32 * wvi + 16 * i, 32 * ks, lane);
#pragma unroll
        for (int j = 0; j < 4; j++) bfr[j] = ld8(KV, 72, 64 * cb + 16 * j, 32 * ks, lane);
#pragma unroll
        for (int i = 0; i < 2; i++)
#pragma unroll
          for (int j = 0; j < 4; j++) acc[i][j] = MFMA(af[i], bfr[j], acc[i][j]);
      }
#pragma unroll
      for (int i = 0; i < 2; i++)
#pragma unroll
        for (int j = 0; j < 4; j++)
#pragma unroll
          for (int r = 0; r < 4; r++) {
            int ml = 32 * wvi + 16 * i + 4 * q4 + r;
            int dd = 64 * cb + 16 * j + c15;
            Sk[scBase + (size_t)(mh * 128 + ml) * 256 + dd] =
                f2bf(acc[i][j][r] * LamH[ml]);
          }
    }
    __syncthreads();
  }

  // stage V^T
  for (int t = 0; t < C_; t++)
    KV[tid * 72 + t] = vg[(size_t)(R0 + t) * D_ + hb + tid];
  __syncthreads();

  for (int mh = 0; mh < 2; mh++) {
    if (tid < 128) {
      int m = mh * 128 + tid;
      float ga = 0.f;
      for (int t = 0; t < C_; t++) {
        float gv = gg[(size_t)(R0 + t) * D_ + hb + m];
        ga += gv;
        Uh[tid * 72 + t] = f2bf((1.f - __expf(gv)) * __expf(-ga));
      }
      LamH[tid] = __expf(ga);
    }
    __syncthreads();
    // Hv^T: [256 v][128 m]; wave rows [64*wvi, +64)
    for (int cb = 0; cb < 2; cb++) {
      f32x4 acc[4][4];
#pragma unroll
      for (int i = 0; i < 4; i++)
#pragma unroll
        for (int j = 0; j < 4; j++) acc[i][j] = zero4();
#pragma unroll
      for (int ks = 0; ks < 2; ks++) {
        bf16x8 af[4], bfr[4];
#pragma unroll
        for (int i = 0; i < 4; i++) af[i] = ld8(KV, 72, 64 * wvi + 16 * i, 32 * ks, lane);
#pragma unroll
        for (int j = 0; j < 4; j++) bfr[j] = ld8(Uh, 72, 64 * cb + 16 * j, 32 * ks, lane);
#pragma unroll
        for (int i = 0; i < 4; i++)
#pragma unroll
          for (int j = 0; j < 4; j++) acc[i][j] = MFMA(af[i], bfr[j], acc[i][j]);
      }
#pragma unroll
      for (int i = 0; i < 4; i++)
#pragma unroll
        for (int j = 0; j < 4; j++)
#pragma unroll
          for (int r = 0; r < 4; r++) {
            int vv = 64 * wvi + 16 * i + 4 * q4 + r;
            int ml = 64 * cb + 16 * j + c15;
            Sv[scBase + (size_t)vv * 256 + mh * 128 + ml] =
                f2bf(acc[i][j][r] * LamH[ml]);
          }
    }
    __syncthreads();
  }
}

// ---------------- K4: chunk-prefix scan (writes entering state per chunk, in place) ----------------
__global__ __launch_bounds__(256) void k_scan(u16* __restrict__ Sk,
                                              u16* __restrict__ Sv,
                                              const float* __restrict__ Lam) {
  const int gid = blockIdx.x * 256 + threadIdx.x;  // 0..262143
  const int st = gid >> 17;
  const int w = gid & 131071;
  const int p = w >> 13;
  const int r = (w >> 5) & 255;
  const int c0 = (w & 31) * 8;
  u16* S = st ? Sv : Sk;
  const size_t base = (size_t)p * NC_ * 65536 + (size_t)r * 256 + c0;
  const float* Lp = Lam + (size_t)p * NC_ * 256;
  float acc[8] = {0, 0, 0, 0, 0, 0, 0, 0};
  for (int c = 0; c < NC_; c++) {
    s16x8 in = *(const s16x8*)(S + base + (size_t)c * 65536);
    s16x8 ov;
#pragma unroll
    for (int j = 0; j < 8; j++) ov[j] = (short)f2bf(acc[j]);
    *(s16x8*)(S + base + (size_t)c * 65536) = ov;  // entering state S_c
    if (st == 0) {
      float lam = Lp[c * 256 + r];
#pragma unroll
      for (int j = 0; j < 8; j++) acc[j] = acc[j] * lam + bf2f((u16)in[j]);
    } else {
#pragma unroll
      for (int j = 0; j < 8; j++) {
        float lam = Lp[c * 256 + c0 + j];
        acc[j] = acc[j] * lam + bf2f((u16)in[j]);
      }
    }
  }
}

// ---------------- K5: per-chunk output ----------------
__global__ __launch_bounds__(256) void k_out(
    const u16* __restrict__ qg, const u16* __restrict__ kg,
    const u16* __restrict__ vg, const float* __restrict__ gg,
    const u16* __restrict__ Sk, const u16* __restrict__ Sv,
    u16* __restrict__ orw) {
  __shared__ __align__(16) char lds[61440];
  u16* As = (u16*)lds;                // [64][72]: masked QK^T, later W
  u16* Ut = (u16*)(lds + 9216);       // [128][72]: U^T half (z phase)
  float* Eh = (float*)(lds + 27648);  // [64][128]: exp(Gc) half
  u16* Pt = (u16*)(lds + 9216);       // [64][264]: P~ (overlaps dead Ut/Eh)
  u16* Vx = (u16*)(lds + 43008);      // [128][72]: U^T regen (W) / V^T half (o)

  const int c = blockIdx.x, p = blockIdx.y;
  const int b = p >> 2, hh = p & 3;
  const int R0 = b * T_ + c * C_, hb = hh * 256;
  const int tid = threadIdx.x, lane = tid & 63, wvi = tid >> 6;
  const int q4 = lane >> 4, c15 = lane & 15;
  const u16* qbase = qg + (size_t)R0 * D_ + hb;
  const u16* kbase = kg + (size_t)R0 * D_ + hb;
  const size_t scBase = ((size_t)p * NC_ + c) * 65536;
  const u16* SkC = Sk + scBase;
  const u16* SvC = Sv + scBase;

  // P1: masked QK^T (both operands streamed from global, d-contiguous)
  {
    f32x4 acc[4];
#pragma unroll
    for (int n = 0; n < 4; n++) acc[n] = zero4();
#pragma unroll
    for (int ks = 0; ks < 8; ks++) {
      bf16x8 af = ld8(qbase, D_, 16 * wvi, 32 * ks, lane);
#pragma unroll
      for (int n = 0; n < 4; n++)
        acc[n] = MFMA(af, ld8(kbase, D_, 16 * n, 32 * ks, lane), acc[n]);
    }
#pragma unroll
    for (int n = 0; n < 4; n++)
#pragma unroll
      for (int r = 0; r < 4; r++) {
        int t = 16 * wvi + 4 * q4 + r, tau = 16 * n + c15;
        As[t * 72 + tau] = f2bf(tau <= t ? acc[n][r] : 0.f);
      }
  }
  __syncthreads();

  // P2: z = E * (As@U + Q@Sk), z kept in regs; E kept in regs for P3
  f32x4 zac[16], eRg[16];
#pragma unroll
  for (int mh = 0; mh < 2; mh++) {
    if (tid < 128) {
      int m = mh * 128 + tid;
      float ga = 0.f;
      for (int t = 0; t < C_; t++) {
        float gv = gg[(size_t)(R0 + t) * D_ + hb + m];
        ga += gv;
        Ut[tid * 72 + t] = f2bf((1.f - __expf(gv)) * __expf(-ga));
        Eh[t * 128 + tid] = __expf(ga);
      }
    }
    __syncthreads();
#pragma unroll
    for (int n = 0; n < 8; n++) zac[mh * 8 + n] = zero4();
#pragma unroll
    for (int ks = 0; ks < 2; ks++) {
      bf16x8 af = ld8(As, 72, 16 * wvi, 32 * ks, lane);
#pragma unroll
      for (int n = 0; n < 8; n++)
        zac[mh * 8 + n] = MFMA(af, ld8(Ut, 72, 16 * n, 32 * ks, lane), zac[mh * 8 + n]);
    }
#pragma unroll
    for (int ks = 0; ks < 8; ks++) {
      bf16x8 af = ld8(qbase, D_, 16 * wvi, 32 * ks, lane);
#pragma unroll
      for (int n = 0; n < 8; n++)
        zac[mh * 8 + n] = MFMA(
            af, ld8(SkC + (size_t)mh * 128 * 256, 256, 16 * n, 32 * ks, lane),
            zac[mh * 8 + n]);
    }
#pragma unroll
    for (int n = 0; n < 8; n++)
#pragma unroll
      for (int r = 0; r < 4; r++) {
        int t = 16 * wvi + 4 * q4 + r;
        float e = Eh[t * 128 + 16 * n + c15];
        eRg[mh * 8 + n][r] = e;
        zac[mh * 8 + n][r] *= e;
      }
    __syncthreads();
  }

  // P3: row softmax (16-lane shuffle groups) + P~ = p * E
#pragma unroll
  for (int r = 0; r < 4; r++) {
    float mx = -3.0e38f;
#pragma unroll
    for (int i = 0; i < 16; i++) mx = fmaxf(mx, zac[i][r]);
    mx = fmaxf(mx, __shfl_xor(mx, 1, 64));
    mx = fmaxf(mx, __shfl_xor(mx, 2, 64));
    mx = fmaxf(mx, __shfl_xor(mx, 4, 64));
    mx = fmaxf(mx, __shfl_xor(mx, 8, 64));
    float sm = 0.f;
#pragma unroll
    for (int i = 0; i < 16; i++) {
      float e = __expf(zac[i][r] - mx);
      zac[i][r] = e;
      sm += e;
    }
    sm += __shfl_xor(sm, 1, 64);
    sm += __shfl_xor(sm, 2, 64);
    sm += __shfl_xor(sm, 4, 64);
    sm += __shfl_xor(sm, 8, 64);
    float inv = 1.f / sm;
#pragma unroll
    for (int i = 0; i < 16; i++) zac[i][r] *= inv * eRg[i][r];
  }
#pragma unroll
  for (int i = 0; i < 16; i++)
#pragma unroll
    for (int r = 0; r < 4; r++) {
      int t = 16 * wvi + 4 * q4 + r;
      int m = (i >> 3) * 128 + 16 * (i & 7) + c15;
      Pt[t * 264 + m] = f2bf(zac[i][r]);
    }
  __syncthreads();

  // P5: W = mask(P~ @ U^T) -> As
  {
    f32x4 wac[4];
#pragma unroll
    for (int n = 0; n < 4; n++) wac[n] = zero4();
    for (int mh = 0; mh < 2; mh++) {
      if (tid < 128) {
        int m = mh * 128 + tid;
        float ga = 0.f;
        for (int t = 0; t < C_; t++) {
          float gv = gg[(size_t)(R0 + t) * D_ + hb + m];
          ga += gv;
          Vx[tid * 72 + t] = f2bf((1.f - __expf(gv)) * __expf(-ga));
        }
      }
      __syncthreads();
#pragma unroll
      for (int ks = 0; ks < 4; ks++) {
        bf16x8 af = ld8(Pt, 264, 16 * wvi, mh * 128 + 32 * ks, lane);
        int mb = 32 * ks + (q4 << 3);
#pragma unroll
        for (int n = 0; n < 4; n++) {
          bf16x8 bfv;
#pragma unroll
          for (int j = 0; j < 8; j++)
            bfv[j] = __builtin_bit_cast(__bf16, (u16)Vx[(mb + j) * 72 + 16 * n + c15]);
          wac[n] = MFMA(af, bfv, wac[n]);
        }
      }
      __syncthreads();
    }
#pragma unroll
    for (int n = 0; n < 4; n++)
#pragma unroll
      for (int r = 0; r < 4; r++) {
        int t = 16 * wvi + 4 * q4 + r, tau = 16 * n + c15;
        As[t * 72 + tau] = f2bf(tau <= t ? wac[n][r] : 0.f);
      }
  }
  __syncthreads();

  // P6: o = P~ @ Sv + W @ V^T
  for (int vh = 0; vh < 2; vh++) {
    if (tid < 128) {
      int v = vh * 128 + tid;
      for (int t = 0; t < C_; t++)
        Vx[tid * 72 + t] = vg[(size_t)(R0 + t) * D_ + hb + v];
    }
    __syncthreads();
    f32x4 oac[8];
#pragma unroll
    for (int n = 0; n < 8; n++) oac[n] = zero4();
#pragma unroll
    for (int ks = 0; ks < 8; ks++) {
      bf16x8 af = ld8(Pt, 264, 16 * wvi, 32 * ks, lane);
#pragma unroll
      for (int n = 0; n < 8; n++)
        oac[n] = MFMA(af, ld8(SvC + (size_t)vh * 128 * 256, 256, 16 * n, 32 * ks, lane), oac[n]);
    }
#pragma unroll
    for (int ks = 0; ks < 2; ks++) {
      bf16x8 af = ld8(As, 72, 16 * wvi, 32 * ks, lane);
#pragma unroll
      for (int n = 0; n < 8; n++)
        oac[n] = MFMA(af, ld8(Vx, 72, 16 * n, 32 * ks, lane), oac[n]);
    }
#pragma unroll
    for (int n = 0; n < 8; n++)
#pragma unroll
      for (int r = 0; r < 4; r++) {
        int t = 16 * wvi + 4 * q4 + r;
        int vc = vh * 128 + 16 * n + c15;
        orw[(size_t)(R0 + t) * D_ + hb + vc] = f2bf(oac[n][r]);
      }
    __syncthreads();
  }
}

extern "C" void kernel_launch(void* const* d_in, const int* in_sizes, int n_in,
                              void* d_out, int out_size, void* d_ws, size_t ws_size,
                              hipStream_t stream) {
  (void)in_sizes; (void)n_in; (void)out_size; (void)ws_size;
  const float* x   = (const float*)d_in[0];
  const float* nw  = (const float*)d_in[1];
  const float* wq  = (const float*)d_in[2];
  const float* wk  = (const float*)d_in[3];
  const float* wvp = (const float*)d_in[4];
  const float* wf  = (const float*)d_in[5];
  const float* gw  = (const float*)d_in[6];
  const float* wo  = (const float*)d_in[7];
  float* out = (float*)d_out;
  char* ws = (char*)d_ws;
  const size_t MB = 1024ull * 1024ull;
  u16*   hbuf = (u16*)(ws);             // 16MB, reused as o_normed
  u16*   qb   = (u16*)(ws + 16 * MB);   // 16MB
  u16*   kb   = (u16*)(ws + 32 * MB);   // 16MB
  u16*   vb   = (u16*)(ws + 48 * MB);   // 16MB
  float* gb   = (float*)(ws + 64 * MB); // 32MB fp32 log-gates
  u16*   SkB  = (u16*)(ws + 96 * MB);   // 64MB states [p][c][m][d]
  u16*   SvB  = (u16*)(ws + 160 * MB);  // 64MB states [p][c][v][m]
  float* Lam  = (float*)(ws + 224 * MB);// 0.5MB chunk decays
  u16*   orw  = (u16*)(ws + 226 * MB);  // 16MB raw attention output
  u16*   wqb  = (u16*)(ws + 242 * MB);  // 2MB bf16 weights
  u16*   wkb  = (u16*)(ws + 244 * MB);
  u16*   wvb  = (u16*)(ws + 246 * MB);
  u16*   wfb  = (u16*)(ws + 248 * MB);
  u16*   wob  = (u16*)(ws + 250 * MB);

  k_cvt<<<dim3(1024), dim3(256), 0, stream>>>(wq, wqb);
  k_cvt<<<dim3(1024), dim3(256), 0, stream>>>(wk, wkb);
  k_cvt<<<dim3(1024), dim3(256), 0, stream>>>(wvp, wvb);
  k_cvt<<<dim3(1024), dim3(256), 0, stream>>>(wf, wfb);
  k_cvt<<<dim3(1024), dim3(256), 0, stream>>>(wo, wob);
  k_rmsnorm<<<dim3(8192), dim3(256), 0, stream>>>(x, nw, hbuf);
  k_gemm<0><<<dim3(64, 8, 4), dim3(256), 0, stream>>>(
      hbuf, wqb, wkb, wvb, wfb, qb, kb, vb, gb, (float*)nullptr);
  k_intra<<<dim3(NC_, 16), dim3(256), 0, stream>>>(kb, vb, gb, SkB, SvB, Lam);
  k_scan<<<dim3(1024), dim3(256), 0, stream>>>(SkB, SvB, Lam);
  k_out<<<dim3(NC_, 16), dim3(256), 0, stream>>>(qb, kb, vb, gb, SkB, SvB, orw);
  k_swishnorm<<<dim3(8192), dim3(256), 0, stream>>>(orw, gw, hbuf);
  k_gemm<1><<<dim3(64, 8, 1), dim3(256), 0, stream>>>(
      hbuf, wob, wob, wob, wob, (u16*)nullptr, (u16*)nullptr, (u16*)nullptr,
      (float*)nullptr, out);
}

// Round 3
// 544.362 us; speedup vs baseline: 1.0442x; 1.0442x over previous
//
#include <hip/hip_runtime.h>
#include <hip/hip_bf16.h>

typedef unsigned short u16;
typedef unsigned int u32;

using bf16x8 = __bf16 __attribute__((ext_vector_type(8)));
using s16x8  = short  __attribute__((ext_vector_type(8)));
using f32x4  = float  __attribute__((ext_vector_type(4)));

#define DEV static __device__ __forceinline__

constexpr int T_ = 2048, D_ = 1024;
constexpr int C_ = 64, NC_ = 32;   // chunk length / count
constexpr float EPS_ = 1e-5f;

DEV float bf2f(u16 u) { return __uint_as_float(((u32)u) << 16); }
DEV u16 f2bf(float f) {
  u32 u = __float_as_uint(f);
  return (u16)((u + 0x7fffu + ((u >> 16) & 1u)) >> 16);
}
DEV float swishf(float x) { return x / (1.f + __expf(-x)); }
DEV f32x4 zero4() { f32x4 z = {0.f, 0.f, 0.f, 0.f}; return z; }

// fragment loader: operand stored [outdim][contract] row-major, 16B/lane
DEV bf16x8 ld8(const u16* p, int ld, int r0, int k0, int lane) {
  return *(const bf16x8*)(p + (size_t)(r0 + (lane & 15)) * ld +
                          (size_t)(k0 + ((lane >> 4) << 3)));
}
DEV f32x4 MFMA(bf16x8 a, bf16x8 b, f32x4 c) {
  return __builtin_amdgcn_mfma_f32_16x16x32_bf16(a, b, c, 0, 0, 0);
}
// direct global->LDS DMA, 16B per lane; LDS dest = wave-uniform base + lane*16
DEV void gld_lds16(const void* g, void* l) {
  __builtin_amdgcn_global_load_lds(
      (const __attribute__((address_space(1))) unsigned int*)g,
      (__attribute__((address_space(3))) unsigned int*)l, 16, 0, 0);
}

// ---------------- K0: fp32 -> bf16 weight conversion (5 weights fused) ----------------
__global__ __launch_bounds__(256) void k_cvt5(
    const float* __restrict__ s0, const float* __restrict__ s1,
    const float* __restrict__ s2, const float* __restrict__ s3,
    const float* __restrict__ s4, u16* __restrict__ d0, u16* __restrict__ d1,
    u16* __restrict__ d2, u16* __restrict__ d3, u16* __restrict__ d4) {
  const int wsel = blockIdx.x >> 10;
  const float* s = (wsel == 0) ? s0 : (wsel == 1) ? s1 : (wsel == 2) ? s2
                   : (wsel == 3) ? s3 : s4;
  u16* d = (wsel == 0) ? d0 : (wsel == 1) ? d1 : (wsel == 2) ? d2
           : (wsel == 3) ? d3 : d4;
  const int i = (blockIdx.x & 1023) * 256 + threadIdx.x;
  float4 v = ((const float4*)s)[i];
  uint2 o;
  o.x = (u32)f2bf(v.x) | ((u32)f2bf(v.y) << 16);
  o.y = (u32)f2bf(v.z) | ((u32)f2bf(v.w) << 16);
  ((uint2*)d)[i] = o;
}

// ---------------- K1: RMSNorm (fp32 in -> bf16 h) ----------------
__global__ __launch_bounds__(256) void k_rmsnorm(const float* __restrict__ x,
                                                 const float* __restrict__ w,
                                                 u16* __restrict__ h) {
  const int row = blockIdx.x, tid = threadIdx.x;
  float4 v = ((const float4*)(x + (size_t)row * D_))[tid];
  float ss = v.x * v.x + v.y * v.y + v.z * v.z + v.w * v.w;
#pragma unroll
  for (int d = 32; d >= 1; d >>= 1) ss += __shfl_xor(ss, d, 64);
  __shared__ float red[4];
  if ((tid & 63) == 0) red[tid >> 6] = ss;
  __syncthreads();
  float rs = rsqrtf((red[0] + red[1] + red[2] + red[3]) * (1.f / D_) + EPS_);
  float4 wv = ((const float4*)w)[tid];
  uint2 o;
  o.x = (u32)f2bf(v.x * rs * wv.x) | ((u32)f2bf(v.y * rs * wv.y) << 16);
  o.y = (u32)f2bf(v.z * rs * wv.z) | ((u32)f2bf(v.w * rs * wv.w) << 16);
  *(uint2*)(h + (size_t)row * D_ + tid * 4) = o;
}

// ---------------- K6: swish + RMSNorm (bf16 in -> bf16) ----------------
__global__ __launch_bounds__(256) void k_swishnorm(const u16* __restrict__ x,
                                                   const float* __restrict__ w,
                                                   u16* __restrict__ o) {
  const int row = blockIdx.x, tid = threadIdx.x;
  uint2 pk = *(const uint2*)(x + (size_t)row * D_ + tid * 4);
  float v0 = swishf(bf2f((u16)(pk.x & 0xffff))), v1 = swishf(bf2f((u16)(pk.x >> 16)));
  float v2 = swishf(bf2f((u16)(pk.y & 0xffff))), v3 = swishf(bf2f((u16)(pk.y >> 16)));
  float ss = v0 * v0 + v1 * v1 + v2 * v2 + v3 * v3;
#pragma unroll
  for (int d = 32; d >= 1; d >>= 1) ss += __shfl_xor(ss, d, 64);
  __shared__ float red[4];
  if ((tid & 63) == 0) red[tid >> 6] = ss;
  __syncthreads();
  float rs = rsqrtf((red[0] + red[1] + red[2] + red[3]) * (1.f / D_) + EPS_);
  float4 wv = ((const float4*)w)[tid];
  uint2 ov;
  ov.x = (u32)f2bf(v0 * rs * wv.x) | ((u32)f2bf(v1 * rs * wv.y) << 16);
  ov.y = (u32)f2bf(v2 * rs * wv.z) | ((u32)f2bf(v3 * rs * wv.w) << 16);
  *(uint2*)(o + (size_t)row * D_ + tid * 4) = ov;
}

// ---------------- K2/K7: NT GEMM  out[8192,1024] = A @ W^T ----------------
// m97-style: global_load_lds width=16 staging, unpadded BK=32 LDS.
// MODE 0: z selects weight; z<3 -> swish->bf16 (q/k/v); z==3 -> logsigmoid/16 -> f32 (g)
// MODE 1: identity -> fp32 (final projection)
template <int MODE>
__global__ __launch_bounds__(256) void k_gemm(
    const u16* __restrict__ A, const u16* __restrict__ w0,
    const u16* __restrict__ w1, const u16* __restrict__ w2,
    const u16* __restrict__ w3, u16* __restrict__ oq, u16* __restrict__ okk,
    u16* __restrict__ ov, float* __restrict__ og, float* __restrict__ ofin) {
  __shared__ __align__(16) u16 As[128 * 32];
  __shared__ __align__(16) u16 Bs[128 * 32];
  const int z = blockIdx.z;
  const u16* W = (z == 0) ? w0 : (z == 1) ? w1 : (z == 2) ? w2 : w3;
  const int m0 = blockIdx.x * 128, n0 = blockIdx.y * 128;
  const int tid = threadIdx.x, lane = tid & 63, wvi = tid >> 6;
  const int wr = wvi >> 1, wc = wvi & 1;
  f32x4 acc[4][4];
#pragma unroll
  for (int i = 0; i < 4; i++)
#pragma unroll
    for (int j = 0; j < 4; j++) acc[i][j] = zero4();
  // staging geometry: one gld_lds16 = 256 lanes x 16B = 64 rows x 32 cols (bf16)
  // wave wvi covers rows [wvi*16, +16); lane i -> row wvi*16 + i/4, col (i%4)*8
  const int srow = tid >> 2, scb = (tid & 3) * 8;
  const u16* Ag = A + (size_t)(m0 + srow) * 1024 + scb;
  const u16* Wg = W + (size_t)(n0 + srow) * 1024 + scb;
  u16* AsW = As + (wvi * 16) * 32;
  u16* BsW = Bs + (wvi * 16) * 32;
  for (int kk = 0; kk < 1024; kk += 32) {
    gld_lds16(Ag + kk, AsW);
    gld_lds16(Ag + kk + 64 * 1024, AsW + 64 * 32);
    gld_lds16(Wg + kk, BsW);
    gld_lds16(Wg + kk + 64 * 1024, BsW + 64 * 32);
    __syncthreads();
    bf16x8 af[4], bfr[4];
#pragma unroll
    for (int i = 0; i < 4; i++) af[i] = ld8(As, 32, wr * 64 + 16 * i, 0, lane);
#pragma unroll
    for (int j = 0; j < 4; j++) bfr[j] = ld8(Bs, 32, wc * 64 + 16 * j, 0, lane);
#pragma unroll
    for (int i = 0; i < 4; i++)
#pragma unroll
      for (int j = 0; j < 4; j++) acc[i][j] = MFMA(af[i], bfr[j], acc[i][j]);
    __syncthreads();
  }
  const int q4 = lane >> 4, c15 = lane & 15;
#pragma unroll
  for (int i = 0; i < 4; i++)
#pragma unroll
    for (int j = 0; j < 4; j++)
#pragma unroll
      for (int r = 0; r < 4; r++) {
        int grow = m0 + wr * 64 + 16 * i + 4 * q4 + r;
        int gcol = n0 + wc * 64 + 16 * j + c15;
        size_t idx = (size_t)grow * 1024 + gcol;
        float val = acc[i][j][r];
        if (MODE == 1) {
          ofin[idx] = val;
        } else if (z < 3) {
          u16* o = (z == 0) ? oq : (z == 1) ? okk : ov;
          o[idx] = f2bf(swishf(val));
        } else {
          float g = (val >= 0.f) ? -log1pf(__expf(-val))
                                 : (val - log1pf(__expf(val)));
          og[idx] = g * (1.0f / 16.0f);
        }
      }
}

// ---------------- K3: per-chunk intra states ----------------
// Sk[(p,c)][m][d] = Lam[m] * sum_tau U[tau,m]*k_tau[d],  U = s*exp(-Gc)
// Sv[(p,c)][v][m] = Lam[m] * sum_tau U[tau,m]*v_tau[v]
__global__ __launch_bounds__(256) void k_intra(
    const u16* __restrict__ kg, const u16* __restrict__ vg,
    const float* __restrict__ gg, u16* __restrict__ Sk, u16* __restrict__ Sv,
    float* __restrict__ Lam) {
  __shared__ __align__(16) u16 KV[256 * 72];   // K^T then V^T  [d/v][tau]
  __shared__ __align__(16) u16 Uh[128 * 72];   // U^T half      [m_loc][tau]
  __shared__ float LamH[128];
  const int c = blockIdx.x, p = blockIdx.y;
  const int b = p >> 2, hh = p & 3;
  const int R0 = b * T_ + c * C_, hb = hh * 256;
  const int tid = threadIdx.x, lane = tid & 63, wvi = tid >> 6;
  const int q4 = lane >> 4, c15 = lane & 15;
  const size_t scBase = ((size_t)p * NC_ + c) * (256 * 256);

  // stage K^T
  for (int t = 0; t < C_; t++)
    KV[tid * 72 + t] = kg[(size_t)(R0 + t) * D_ + hb + tid];
  __syncthreads();

  for (int mh = 0; mh < 2; mh++) {
    if (tid < 128) {
      int m = mh * 128 + tid;
      float ga = 0.f;
      for (int t = 0; t < C_; t++) {
        float gv = gg[(size_t)(R0 + t) * D_ + hb + m];
        ga += gv;
        Uh[tid * 72 + t] = f2bf((1.f - __expf(gv)) * __expf(-ga));
      }
      float lam = __expf(ga);
      LamH[tid] = lam;
      Lam[((size_t)p * NC_ + c) * 256 + m] = lam;
    }
    __syncthreads();
    // Hk^T half: [128 m][256 d]; wave rows [32*wvi, +32)
    for (int cb = 0; cb < 4; cb++) {
      f32x4 acc[2][4];
#pragma unroll
      for (int i = 0; i < 2; i++)
#pragma unroll
        for (int j = 0; j < 4; j++) acc[i][j] = zero4();
#pragma unroll
      for (int ks = 0; ks < 2; ks++) {
        bf16x8 af[2], bfr[4];
#pragma unroll
        for (int i = 0; i < 2; i++) af[i] = ld8(Uh, 72, 32 * wvi + 16 * i, 32 * ks, lane);
#pragma unroll
        for (int j = 0; j < 4; j++) bfr[j] = ld8(KV, 72, 64 * cb + 16 * j, 32 * ks, lane);
#pragma unroll
        for (int i = 0; i < 2; i++)
#pragma unroll
          for (int j = 0; j < 4; j++) acc[i][j] = MFMA(af[i], bfr[j], acc[i][j]);
      }
#pragma unroll
      for (int i = 0; i < 2; i++)
#pragma unroll
        for (int j = 0; j < 4; j++)
#pragma unroll
          for (int r = 0; r < 4; r++) {
            int ml = 32 * wvi + 16 * i + 4 * q4 + r;
            int dd = 64 * cb + 16 * j + c15;
            Sk[scBase + (size_t)(mh * 128 + ml) * 256 + dd] =
                f2bf(acc[i][j][r] * LamH[ml]);
          }
    }
    __syncthreads();
  }

  // stage V^T
  for (int t = 0; t < C_; t++)
    KV[tid * 72 + t] = vg[(size_t)(R0 + t) * D_ + hb + tid];
  __syncthreads();

  for (int mh = 0; mh < 2; mh++) {
    if (tid < 128) {
      int m = mh * 128 + tid;
      float ga = 0.f;
      for (int t = 0; t < C_; t++) {
        float gv = gg[(size_t)(R0 + t) * D_ + hb + m];
        ga += gv;
        Uh[tid * 72 + t] = f2bf((1.f - __expf(gv)) * __expf(-ga));
      }
      LamH[tid] = __expf(ga);
    }
    __syncthreads();
    // Hv^T: [256 v][128 m]; wave rows [64*wvi, +64)
    for (int cb = 0; cb < 2; cb++) {
      f32x4 acc[4][4];
#pragma unroll
      for (int i = 0; i < 4; i++)
#pragma unroll
        for (int j = 0; j < 4; j++) acc[i][j] = zero4();
#pragma unroll
      for (int ks = 0; ks < 2; ks++) {
        bf16x8 af[4], bfr[4];
#pragma unroll
        for (int i = 0; i < 4; i++) af[i] = ld8(KV, 72, 64 * wvi + 16 * i, 32 * ks, lane);
#pragma unroll
        for (int j = 0; j < 4; j++) bfr[j] = ld8(Uh, 72, 64 * cb + 16 * j, 32 * ks, lane);
#pragma unroll
        for (int i = 0; i < 4; i++)
#pragma unroll
          for (int j = 0; j < 4; j++) acc[i][j] = MFMA(af[i], bfr[j], acc[i][j]);
      }
#pragma unroll
      for (int i = 0; i < 4; i++)
#pragma unroll
        for (int j = 0; j < 4; j++)
#pragma unroll
          for (int r = 0; r < 4; r++) {
            int vv = 64 * wvi + 16 * i + 4 * q4 + r;
            int ml = 64 * cb + 16 * j + c15;
            Sv[scBase + (size_t)vv * 256 + mh * 128 + ml] =
                f2bf(acc[i][j][r] * LamH[ml]);
          }
    }
    __syncthreads();
  }
}

// ---------------- K4: chunk-prefix scan (writes entering state per chunk, in place) ----------------
__global__ __launch_bounds__(256) void k_scan(u16* __restrict__ Sk,
                                              u16* __restrict__ Sv,
                                              const float* __restrict__ Lam) {
  const int gid = blockIdx.x * 256 + threadIdx.x;  // 0..262143
  const int st = gid >> 17;
  const int w = gid & 131071;
  const int p = w >> 13;
  const int r = (w >> 5) & 255;
  const int c0 = (w & 31) * 8;
  u16* S = st ? Sv : Sk;
  const size_t base = (size_t)p * NC_ * 65536 + (size_t)r * 256 + c0;
  const float* Lp = Lam + (size_t)p * NC_ * 256;
  float acc[8] = {0, 0, 0, 0, 0, 0, 0, 0};
  for (int c = 0; c < NC_; c++) {
    s16x8 in = *(const s16x8*)(S + base + (size_t)c * 65536);
    s16x8 ov;
#pragma unroll
    for (int j = 0; j < 8; j++) ov[j] = (short)f2bf(acc[j]);
    *(s16x8*)(S + base + (size_t)c * 65536) = ov;  // entering state S_c
    if (st == 0) {
      float lam = Lp[c * 256 + r];
#pragma unroll
      for (int j = 0; j < 8; j++) acc[j] = acc[j] * lam + bf2f((u16)in[j]);
    } else {
#pragma unroll
      for (int j = 0; j < 8; j++) {
        float lam = Lp[c * 256 + c0 + j];
        acc[j] = acc[j] * lam + bf2f((u16)in[j]);
      }
    }
  }
}

// ---------------- K5: per-chunk output ----------------
__global__ __launch_bounds__(256) void k_out(
    const u16* __restrict__ qg, const u16* __restrict__ kg,
    const u16* __restrict__ vg, const float* __restrict__ gg,
    const u16* __restrict__ Sk, const u16* __restrict__ Sv,
    u16* __restrict__ orw) {
  __shared__ __align__(16) char lds[61440];
  u16* As = (u16*)lds;                // [64][72]: masked QK^T, later W
  u16* Ut = (u16*)(lds + 9216);       // [128][72]: U^T half (z phase)
  float* Eh = (float*)(lds + 27648);  // [64][128]: exp(Gc) half
  u16* Pt = (u16*)(lds + 9216);       // [64][264]: P~ (overlaps dead Ut/Eh)
  u16* Vx = (u16*)(lds + 43008);      // [128][72]: U^T regen (W) / V^T half (o)

  const int c = blockIdx.x, p = blockIdx.y;
  const int b = p >> 2, hh = p & 3;
  const int R0 = b * T_ + c * C_, hb = hh * 256;
  const int tid = threadIdx.x, lane = tid & 63, wvi = tid >> 6;
  const int q4 = lane >> 4, c15 = lane & 15;
  const u16* qbase = qg + (size_t)R0 * D_ + hb;
  const u16* kbase = kg + (size_t)R0 * D_ + hb;
  const size_t scBase = ((size_t)p * NC_ + c) * 65536;
  const u16* SkC = Sk + scBase;
  const u16* SvC = Sv + scBase;

  // P1: masked QK^T (both operands streamed from global, d-contiguous)
  {
    f32x4 acc[4];
#pragma unroll
    for (int n = 0; n < 4; n++) acc[n] = zero4();
#pragma unroll
    for (int ks = 0; ks < 8; ks++) {
      bf16x8 af = ld8(qbase, D_, 16 * wvi, 32 * ks, lane);
#pragma unroll
      for (int n = 0; n < 4; n++)
        acc[n] = MFMA(af, ld8(kbase, D_, 16 * n, 32 * ks, lane), acc[n]);
    }
#pragma unroll
    for (int n = 0; n < 4; n++)
#pragma unroll
      for (int r = 0; r < 4; r++) {
        int t = 16 * wvi + 4 * q4 + r, tau = 16 * n + c15;
        As[t * 72 + tau] = f2bf(tau <= t ? acc[n][r] : 0.f);
      }
  }
  __syncthreads();

  // P2: z = E * (As@U + Q@Sk), z kept in regs; E kept in regs for P3
  f32x4 zac[16], eRg[16];
#pragma unroll
  for (int mh = 0; mh < 2; mh++) {
    if (tid < 128) {
      int m = mh * 128 + tid;
      float ga = 0.f;
      for (int t = 0; t < C_; t++) {
        float gv = gg[(size_t)(R0 + t) * D_ + hb + m];
        ga += gv;
        Ut[tid * 72 + t] = f2bf((1.f - __expf(gv)) * __expf(-ga));
        Eh[t * 128 + tid] = __expf(ga);
      }
    }
    __syncthreads();
#pragma unroll
    for (int n = 0; n < 8; n++) zac[mh * 8 + n] = zero4();
#pragma unroll
    for (int ks = 0; ks < 2; ks++) {
      bf16x8 af = ld8(As, 72, 16 * wvi, 32 * ks, lane);
#pragma unroll
      for (int n = 0; n < 8; n++)
        zac[mh * 8 + n] = MFMA(af, ld8(Ut, 72, 16 * n, 32 * ks, lane), zac[mh * 8 + n]);
    }
#pragma unroll
    for (int ks = 0; ks < 8; ks++) {
      bf16x8 af = ld8(qbase, D_, 16 * wvi, 32 * ks, lane);
#pragma unroll
      for (int n = 0; n < 8; n++)
        zac[mh * 8 + n] = MFMA(
            af, ld8(SkC + (size_t)mh * 128 * 256, 256, 16 * n, 32 * ks, lane),
            zac[mh * 8 + n]);
    }
#pragma unroll
    for (int n = 0; n < 8; n++)
#pragma unroll
      for (int r = 0; r < 4; r++) {
        int t = 16 * wvi + 4 * q4 + r;
        float e = Eh[t * 128 + 16 * n + c15];
        eRg[mh * 8 + n][r] = e;
        zac[mh * 8 + n][r] *= e;
      }
    __syncthreads();
  }

  // P3: row softmax (16-lane shuffle groups) + P~ = p * E
#pragma unroll
  for (int r = 0; r < 4; r++) {
    float mx = -3.0e38f;
#pragma unroll
    for (int i = 0; i < 16; i++) mx = fmaxf(mx, zac[i][r]);
    mx = fmaxf(mx, __shfl_xor(mx, 1, 64));
    mx = fmaxf(mx, __shfl_xor(mx, 2, 64));
    mx = fmaxf(mx, __shfl_xor(mx, 4, 64));
    mx = fmaxf(mx, __shfl_xor(mx, 8, 64));
    float sm = 0.f;
#pragma unroll
    for (int i = 0; i < 16; i++) {
      float e = __expf(zac[i][r] - mx);
      zac[i][r] = e;
      sm += e;
    }
    sm += __shfl_xor(sm, 1, 64);
    sm += __shfl_xor(sm, 2, 64);
    sm += __shfl_xor(sm, 4, 64);
    sm += __shfl_xor(sm, 8, 64);
    float inv = 1.f / sm;
#pragma unroll
    for (int i = 0; i < 16; i++) zac[i][r] *= inv * eRg[i][r];
  }
#pragma unroll
  for (int i = 0; i < 16; i++)
#pragma unroll
    for (int r = 0; r < 4; r++) {
      int t = 16 * wvi + 4 * q4 + r;
      int m = (i >> 3) * 128 + 16 * (i & 7) + c15;
      Pt[t * 264 + m] = f2bf(zac[i][r]);
    }
  __syncthreads();

  // P5: W = mask(P~ @ U^T) -> As
  {
    f32x4 wac[4];
#pragma unroll
    for (int n = 0; n < 4; n++) wac[n] = zero4();
    for (int mh = 0; mh < 2; mh++) {
      if (tid < 128) {
        int m = mh * 128 + tid;
        float ga = 0.f;
        for (int t = 0; t < C_; t++) {
          float gv = gg[(size_t)(R0 + t) * D_ + hb + m];
          ga += gv;
          Vx[tid * 72 + t] = f2bf((1.f - __expf(gv)) * __expf(-ga));
        }
      }
      __syncthreads();
#pragma unroll
      for (int ks = 0; ks < 4; ks++) {
        bf16x8 af = ld8(Pt, 264, 16 * wvi, mh * 128 + 32 * ks, lane);
        int mb = 32 * ks + (q4 << 3);
#pragma unroll
        for (int n = 0; n < 4; n++) {
          bf16x8 bfv;
#pragma unroll
          for (int j = 0; j < 8; j++)
            bfv[j] = __builtin_bit_cast(__bf16, (u16)Vx[(mb + j) * 72 + 16 * n + c15]);
          wac[n] = MFMA(af, bfv, wac[n]);
        }
      }
      __syncthreads();
    }
#pragma unroll
    for (int n = 0; n < 4; n++)
#pragma unroll
      for (int r = 0; r < 4; r++) {
        int t = 16 * wvi + 4 * q4 + r, tau = 16 * n + c15;
        As[t * 72 + tau] = f2bf(tau <= t ? wac[n][r] : 0.f);
      }
  }
  __syncthreads();

  // P6: o = P~ @ Sv + W @ V^T
  for (int vh = 0; vh < 2; vh++) {
    if (tid < 128) {
      int v = vh * 128 + tid;
      for (int t = 0; t < C_; t++)
        Vx[tid * 72 + t] = vg[(size_t)(R0 + t) * D_ + hb + v];
    }
    __syncthreads();
    f32x4 oac[8];
#pragma unroll
    for (int n = 0; n < 8; n++) oac[n] = zero4();
#pragma unroll
    for (int ks = 0; ks < 8; ks++) {
      bf16x8 af = ld8(Pt, 264, 16 * wvi, 32 * ks, lane);
#pragma unroll
      for (int n = 0; n < 8; n++)
        oac[n] = MFMA(af, ld8(SvC + (size_t)vh * 128 * 256, 256, 16 * n, 32 * ks, lane), oac[n]);
    }
#pragma unroll
    for (int ks = 0; ks < 2; ks++) {
      bf16x8 af = ld8(As, 72, 16 * wvi, 32 * ks, lane);
#pragma unroll
      for (int n = 0; n < 8; n++)
        oac[n] = MFMA(af, ld8(Vx, 72, 16 * n, 32 * ks, lane), oac[n]);
    }
#pragma unroll
    for (int n = 0; n < 8; n++)
#pragma unroll
      for (int r = 0; r < 4; r++) {
        int t = 16 * wvi + 4 * q4 + r;
        int vc = vh * 128 + 16 * n + c15;
        orw[(size_t)(R0 + t) * D_ + hb + vc] = f2bf(oac[n][r]);
      }
    __syncthreads();
  }
}

extern "C" void kernel_launch(void* const* d_in, const int* in_sizes, int n_in,
                              void* d_out, int out_size, void* d_ws, size_t ws_size,
                              hipStream_t stream) {
  (void)in_sizes; (void)n_in; (void)out_size; (void)ws_size;
  const float* x   = (const float*)d_in[0];
  const float* nw  = (const float*)d_in[1];
  const float* wq  = (const float*)d_in[2];
  const float* wk  = (const float*)d_in[3];
  const float* wvp = (const float*)d_in[4];
  const float* wf  = (const float*)d_in[5];
  const float* gw  = (const float*)d_in[6];
  const float* wo  = (const float*)d_in[7];
  float* out = (float*)d_out;
  char* ws = (char*)d_ws;
  const size_t MB = 1024ull * 1024ull;
  u16*   hbuf = (u16*)(ws);             // 16MB, reused as o_normed
  u16*   qb   = (u16*)(ws + 16 * MB);   // 16MB
  u16*   kb   = (u16*)(ws + 32 * MB);   // 16MB
  u16*   vb   = (u16*)(ws + 48 * MB);   // 16MB
  float* gb   = (float*)(ws + 64 * MB); // 32MB fp32 log-gates
  u16*   SkB  = (u16*)(ws + 96 * MB);   // 64MB states [p][c][m][d]
  u16*   SvB  = (u16*)(ws + 160 * MB);  // 64MB states [p][c][v][m]
  float* Lam  = (float*)(ws + 224 * MB);// 0.5MB chunk decays
  u16*   orw  = (u16*)(ws + 226 * MB);  // 16MB raw attention output
  u16*   wqb  = (u16*)(ws + 242 * MB);  // 2MB bf16 weights
  u16*   wkb  = (u16*)(ws + 244 * MB);
  u16*   wvb  = (u16*)(ws + 246 * MB);
  u16*   wfb  = (u16*)(ws + 248 * MB);
  u16*   wob  = (u16*)(ws + 250 * MB);

  k_cvt5<<<dim3(5120), dim3(256), 0, stream>>>(wq, wk, wvp, wf, wo,
                                               wqb, wkb, wvb, wfb, wob);
  k_rmsnorm<<<dim3(8192), dim3(256), 0, stream>>>(x, nw, hbuf);
  k_gemm<0><<<dim3(64, 8, 4), dim3(256), 0, stream>>>(
      hbuf, wqb, wkb, wvb, wfb, qb, kb, vb, gb, (float*)nullptr);
  k_intra<<<dim3(NC_, 16), dim3(256), 0, stream>>>(kb, vb, gb, SkB, SvB, Lam);
  k_scan<<<dim3(1024), dim3(256), 0, stream>>>(SkB, SvB, Lam);
  k_out<<<dim3(NC_, 16), dim3(256), 0, stream>>>(qb, kb, vb, gb, SkB, SvB, orw);
  k_swishnorm<<<dim3(8192), dim3(256), 0, stream>>>(orw, gw, hbuf);
  k_gemm<1><<<dim3(64, 8, 1), dim3(256), 0, stream>>>(
      hbuf, wob, wob, wob, wob, (u16*)nullptr, (u16*)nullptr, (u16*)nullptr,
      (float*)nullptr, out);
}